// Round 6
// baseline (1070.981 us; speedup 1.0000x reference)
//
#include <hip/hip_runtime.h>
#include <math.h>

#define Nrows 16384          // B*H*W
#define NE 8192
#define Kdim 256
#define HWsz 1024
#define NSPL 16              // code-group splits (cg)
#define BETAF 0.25f

typedef __attribute__((ext_vector_type(8))) short bf16x8;
typedef __attribute__((ext_vector_type(16))) float f32x16;
typedef unsigned short u16;

__device__ inline u16 bf16_rne(float x) {
  unsigned int u = __float_as_uint(x);
  return (u16)((u + 0x7FFFu + ((u >> 16) & 1u)) >> 16);
}
__device__ inline float bf16_tof(u16 h) {
  return __uint_as_float(((unsigned int)h) << 16);
}
__device__ inline void gll16(const void* g, void* l) {
  __builtin_amdgcn_global_load_lds(
      (const __attribute__((address_space(1))) unsigned int*)g,
      (__attribute__((address_space(3))) unsigned int*)l, 16, 0, 0);
}

// ---- cc[j] = sum_k codebook[j][k]^2 (identical math to r1-r5) -------------
__global__ __launch_bounds__(256) void cc_kernel(const float* __restrict__ cb,
                                                 float* __restrict__ cc) {
  int wave = threadIdx.x >> 6;
  int lane = threadIdx.x & 63;
  int row = blockIdx.x * 4 + wave;
  const float4 v = *(const float4*)(cb + (size_t)row * Kdim + lane * 4);
  float s = v.x * v.x + v.y * v.y + v.z * v.z + v.w * v.w;
  for (int off = 32; off; off >>= 1) s += __shfl_down(s, off);
  if (lane == 0) cc[row] = s;
}

// ---- codebook -> frag-order bf16 splits Cf (unchanged from r4/r5) ---------
// Group (j32, arr, k16) of 512 u16 at ((j32*3+arr)*16 + k16)*512;
// within group: (khalf*32 + j%32)*8 + i.
__global__ __launch_bounds__(256) void conv_cb(const float* __restrict__ cb,
                                               u16* __restrict__ Cf) {
  const int g = blockIdx.x * 256 + threadIdx.x;   // 0 .. 8192*16-1
  const int j = g >> 4, k16 = g & 15;
  const float* src = cb + (size_t)j * Kdim + k16 * 16;
  float f[16];
#pragma unroll
  for (int q = 0; q < 4; ++q) {
    const float4 v = ((const float4*)src)[q];
    f[q * 4 + 0] = v.x; f[q * 4 + 1] = v.y; f[q * 4 + 2] = v.z; f[q * 4 + 3] = v.w;
  }
  u16 h[3][16];
#pragma unroll
  for (int i = 0; i < 16; ++i) {
    const u16 q0 = bf16_rne(f[i]);
    const float r1 = f[i] - bf16_tof(q0);
    const u16 q1 = bf16_rne(r1);
    const float r2 = r1 - bf16_tof(q1);
    h[0][i] = q0; h[1][i] = q1; h[2][i] = bf16_rne(r2);
  }
  const int j32 = j >> 5, li = j & 31;
#pragma unroll
  for (int arr = 0; arr < 3; ++arr) {
#pragma unroll
    for (int kh = 0; kh < 2; ++kh) {
      const size_t off = ((size_t)(j32 * 3 + arr) * 16 + k16) * 512 + (kh * 32 + li) * 8;
      *(int4*)(Cf + off) = *(int4*)&h[arr][kh * 8];
    }
  }
}

// ---- z (B,C,H,W) -> frag-order bf16 splits Zf + zz (unchanged from r4/r5) -
__global__ __launch_bounds__(256) void conv_z(const float* __restrict__ z,
                                              u16* __restrict__ Zf,
                                              float* __restrict__ zz) {
  __shared__ float tile[64][68];
  const int t = threadIdx.x;
  const int bid = blockIdx.x;
  const int n0 = bid * 64;
  const int b = bid >> 4;
  const int hw0 = (bid & 15) << 6;
  const float* zb = z + (size_t)b * (Kdim * HWsz) + hw0;
  float zzacc = 0.f;
  const int rr = t >> 2;
  const int kq = (t & 3) * 16;
  for (int kc = 0; kc < 4; ++kc) {
#pragma unroll
    for (int i = 0; i < 16; ++i) {
      const int idx = i * 256 + t;
      const int k = idx >> 6, r = idx & 63;
      tile[r][k] = zb[(size_t)(kc * 64 + k) * HWsz + r];
    }
    __syncthreads();
    if (t < 64) {
      for (int k = 0; k < 64; ++k) {
        const float a = tile[t][k];
        zzacc = fmaf(a, a, zzacc);
      }
    }
    u16 h[3][16];
#pragma unroll
    for (int i = 0; i < 16; ++i) {
      const float fv = tile[rr][kq + i];
      const u16 q0 = bf16_rne(fv);
      const float r1 = fv - bf16_tof(q0);
      const u16 q1 = bf16_rne(r1);
      const float r2 = r1 - bf16_tof(q1);
      h[0][i] = q0; h[1][i] = q1; h[2][i] = bf16_rne(r2);
    }
    const int k16 = kc * 4 + (t & 3);
    const int n32 = bid * 2 + (rr >> 5), li = rr & 31;
#pragma unroll
    for (int arr = 0; arr < 3; ++arr) {
#pragma unroll
      for (int kh = 0; kh < 2; ++kh) {
        const size_t off = ((size_t)(n32 * 3 + arr) * 16 + k16) * 512 + (kh * 32 + li) * 8;
        *(int4*)(Zf + off) = *(int4*)&h[arr][kh * 8];
      }
    }
    __syncthreads();
  }
  if (t < 64) zz[n0 + t] = zzacc;
}

// ---- main GEMM+argmin: rows L2-pinned per XCD, codebook streamed via LDS --
// Grid 256 = 16 cg x 16 rg, bid = cg*16+rg -> XCD = bid%8 = rg%8: all 16
// cg-blocks of a row-group share one XCD, so the rg's 1.5 MB Zf slice stays
// L2-resident while Z is re-read once per 64-code tile. Block 1024 thr /
// 16 waves (4/SIMD); wave owns 64 rows exclusively; codes stream through a
// single-buffered 96 KB LDS A-tile (8 tiles of 64 codes = 512 codes/block).
__global__ __launch_bounds__(1024) void vq_gemm(
    const u16* __restrict__ Cf, const u16* __restrict__ Zf,
    const float* __restrict__ cc, const float* __restrict__ zz,
    float* __restrict__ pd, int* __restrict__ pj) {
  __shared__ u16 Al[49152];        // 96 KB: group ((jx*3+arr)*16+k16)*512
  __shared__ float ccs[512];

  const int t = threadIdx.x;
  const int lane = t & 63;
  const int w = __builtin_amdgcn_readfirstlane(t >> 6);
  const int bid = blockIdx.x;
  const int cg = bid >> 4;         // code group (0..15), 512 codes
  const int rg = bid & 15;         // row group (0..15), 1024 rows; XCD=rg%8

  if (t < 512) ccs[t] = cc[cg * 512 + t];

  float zzv[2];
  zzv[0] = zz[rg * 1024 + w * 64 + (lane & 31)];
  zzv[1] = zz[rg * 1024 + w * 64 + 32 + (lane & 31)];

  float bd[2] = {INFINITY, INFINITY};
  int bj[2] = {0, 0};
  const f32x16 zero16 = {0,0,0,0,0,0,0,0,0,0,0,0,0,0,0,0};

  for (int ct = 0; ct < 8; ++ct) {
    __syncthreads();   // all waves done reading previous A-tile
    // stage 64-code tile: 96 groups of 1 KB, 6 per wave (dest=base+lane*16)
#pragma unroll
    for (int i = 0; i < 6; ++i) {
      const int g = w * 6 + i;
      const int ja = g >> 4;                 // jx*3+arr (0..5)
      const int jx = ja / 3, arr = ja % 3;
      const int k16 = g & 15;
      gll16(Cf + ((size_t)((cg * 16 + ct * 2 + jx) * 3 + arr) * 16 + k16) * 512 + lane * 8,
            &Al[g * 512]);
    }
    __syncthreads();   // drains vmcnt -> tile visible

    f32x16 acc[2][2];
    acc[0][0] = zero16; acc[0][1] = zero16; acc[1][0] = zero16; acc[1][1] = zero16;

    for (int ch = 0; ch < 16; ++ch) {
      bf16x8 af[3][2], bfr[3][2];
#pragma unroll
      for (int arr = 0; arr < 3; ++arr) {
#pragma unroll
        for (int x = 0; x < 2; ++x) {
          af[arr][x] = *(const bf16x8*)&Al[((x * 3 + arr) * 16 + ch) * 512 + lane * 8];
          bfr[arr][x] = *(const bf16x8*)(
              Zf + ((size_t)((rg * 32 + w * 2 + x) * 3 + arr) * 16 + ch) * 512 + lane * 8);
        }
      }
#define PROD(pa, pb) \
  acc[0][0] = __builtin_amdgcn_mfma_f32_32x32x16_bf16(af[pa][0], bfr[pb][0], acc[0][0], 0, 0, 0); \
  acc[0][1] = __builtin_amdgcn_mfma_f32_32x32x16_bf16(af[pa][0], bfr[pb][1], acc[0][1], 0, 0, 0); \
  acc[1][0] = __builtin_amdgcn_mfma_f32_32x32x16_bf16(af[pa][1], bfr[pb][0], acc[1][0], 0, 0, 0); \
  acc[1][1] = __builtin_amdgcn_mfma_f32_32x32x16_bf16(af[pa][1], bfr[pb][1], acc[1][1], 0, 0, 0);
      PROD(0, 0) PROD(0, 1) PROD(1, 0) PROD(1, 1) PROD(0, 2) PROD(2, 0)
#undef PROD
    }

    // epilogue: d = (zz + cc) - 2*acc, ascending j per lane (same as r3-r5)
#pragma unroll
    for (int ci = 0; ci < 2; ++ci) {
#pragma unroll
      for (int ri = 0; ri < 2; ++ri) {
#pragma unroll
        for (int reg = 0; reg < 16; ++reg) {
          const int cl = ct * 64 + ci * 32 +
                         (reg & 3) + ((reg >> 2) * 8) + ((lane >> 5) * 4);
          const float d = (zzv[ri] + ccs[cl]) - 2.0f * acc[ci][ri][reg];
          const int j = cg * 512 + cl;
          if (d < bd[ri]) { bd[ri] = d; bj[ri] = j; }
        }
      }
    }
  }

  // combine lane halves (same z-rows, complementary code sub-columns);
  // each row lives in exactly one wave -> no cross-wave reduction needed.
#pragma unroll
  for (int ri = 0; ri < 2; ++ri) {
    const float od = __shfl_xor(bd[ri], 32);
    const int oj = __shfl_xor(bj[ri], 32);
    if (od < bd[ri] || (od == bd[ri] && oj < bj[ri])) { bd[ri] = od; bj[ri] = oj; }
  }
  if (lane < 32) {
#pragma unroll
    for (int ri = 0; ri < 2; ++ri) {
      const int n = rg * 1024 + w * 64 + ri * 32 + lane;
      pd[(size_t)cg * Nrows + n] = bd[ri];
      pj[(size_t)cg * Nrows + n] = bj[ri];
    }
  }
}

// ---- combine 16 code-group partials -> idx, counts ------------------------
__global__ __launch_bounds__(256) void vq_combine(const float* __restrict__ pd,
                                                  const int* __restrict__ pj,
                                                  int* __restrict__ idx_int,
                                                  float* __restrict__ out_idxf,
                                                  int* __restrict__ counts) {
  const int n = blockIdx.x * 256 + threadIdx.x;
  float d0 = pd[n];
  int j0 = pj[n];
  for (int s = 1; s < NSPL; ++s) {
    const float d = pd[(size_t)s * Nrows + n];
    const int j = pj[(size_t)s * Nrows + n];
    if (d < d0 || (d == d0 && j < j0)) { d0 = d; j0 = j; }
  }
  idx_int[n] = j0;
  out_idxf[n] = (float)j0;
  atomicAdd(&counts[j0], 1);
}

// ---- gather zq (BCHW) + loss sum (unchanged, passed r1-r5) ----------------
__global__ __launch_bounds__(256) void vq_gather_loss(
    const float* __restrict__ z, const float* __restrict__ cb,
    const int* __restrict__ idx_int, float* __restrict__ outz,
    float* __restrict__ loss_sum) {
  const int g = blockIdx.x * 256 + threadIdx.x;
  const int hw4 = g & 255;
  const int c = (g >> 8) & 255;
  const int b = g >> 16;
  const int n = b * HWsz + hw4 * 4;
  const float4 zv = *(const float4*)(z + (size_t)g * 4);
  const int4 j4 = *(const int4*)(idx_int + n);
  float4 q;
  q.x = cb[(size_t)j4.x * Kdim + c];
  q.y = cb[(size_t)j4.y * Kdim + c];
  q.z = cb[(size_t)j4.z * Kdim + c];
  q.w = cb[(size_t)j4.w * Kdim + c];
  *(float4*)(outz + (size_t)g * 4) = q;
  float dx = q.x - zv.x, dy = q.y - zv.y, dz = q.z - zv.z, dw = q.w - zv.w;
  float s = dx * dx + dy * dy + dz * dz + dw * dw;
  for (int off = 32; off; off >>= 1) s += __shfl_down(s, off);
  __shared__ float ws4[4];
  if ((threadIdx.x & 63) == 0) ws4[threadIdx.x >> 6] = s;
  __syncthreads();
  if (threadIdx.x == 0) atomicAdd(loss_sum, (ws4[0] + ws4[1]) + (ws4[2] + ws4[3]));
}

// ---- scalars (unchanged) --------------------------------------------------
__global__ __launch_bounds__(256) void vq_final(const int* __restrict__ counts,
                                                const float* __restrict__ loss_sum,
                                                float* __restrict__ out_sc) {
  float h = 0.f;
  for (int i = threadIdx.x; i < NE; i += 256) {
    float p = (float)counts[i] * (1.0f / 16384.0f);
    h += p * logf(p + 1e-10f);
  }
  for (int off = 32; off; off >>= 1) h += __shfl_down(h, off);
  __shared__ float hs[4];
  if ((threadIdx.x & 63) == 0) hs[threadIdx.x >> 6] = h;
  __syncthreads();
  if (threadIdx.x == 0) {
    float H = (hs[0] + hs[1]) + (hs[2] + hs[3]);
    float m = loss_sum[0] * (1.0f / 4194304.0f);
    out_sc[0] = m + BETAF * m;
    out_sc[1] = expf(-H);
  }
}

extern "C" void kernel_launch(void* const* d_in, const int* in_sizes, int n_in,
                              void* d_out, int out_size, void* d_ws, size_t ws_size,
                              hipStream_t stream) {
  const float* z = (const float*)d_in[0];
  const float* cb = (const float*)d_in[1];
  float* out = (float*)d_out;
  float* out_zq = out;                     // 4194304
  float* out_sc = out + 4194304;           // loss, perplexity
  float* out_idx = out + 4194306;          // 16384 idx as float

  char* wp = (char*)d_ws;
  u16* Cf = (u16*)wp;           wp += (size_t)NE * Kdim * 2 * 3;
  u16* Zf = (u16*)wp;           wp += (size_t)Nrows * Kdim * 2 * 3;
  float* cc = (float*)wp;       wp += (size_t)NE * 4;
  float* zz = (float*)wp;       wp += (size_t)Nrows * 4;
  float* pd = (float*)wp;       wp += (size_t)NSPL * Nrows * 4;
  int* pj = (int*)wp;           wp += (size_t)NSPL * Nrows * 4;
  int* idx_int = (int*)wp;      wp += (size_t)Nrows * 4;
  int* counts = (int*)wp;       wp += (size_t)NE * 4;
  float* loss_sum = (float*)wp; wp += 64;

  hipMemsetAsync(counts, 0, (size_t)NE * 4, stream);
  hipMemsetAsync(loss_sum, 0, 4, stream);

  cc_kernel<<<NE / 4, 256, 0, stream>>>(cb, cc);
  conv_cb<<<NE * 16 / 256, 256, 0, stream>>>(cb, Cf);
  conv_z<<<Nrows / 64, 256, 0, stream>>>(z, Zf, zz);
  vq_gemm<<<256, 1024, 0, stream>>>(Cf, Zf, cc, zz, pd, pj);
  vq_combine<<<Nrows / 256, 256, 0, stream>>>(pd, pj, idx_int, out_idx, counts);
  vq_gather_loss<<<4096, 256, 0, stream>>>(z, cb, idx_int, out_zq, loss_sum);
  vq_final<<<1, 256, 0, stream>>>(counts, loss_sum, out_sc);
}

// Round 7
// 470.783 us; speedup vs baseline: 2.2749x; 2.2749x over previous
//
#include <hip/hip_runtime.h>
#include <math.h>

#define Nrows 16384          // B*H*W
#define NE 8192
#define Kdim 256
#define HWsz 1024
#define NSPL 4               // code-group splits (cg)
#define BETAF 0.25f

typedef __attribute__((ext_vector_type(8))) short bf16x8;
typedef __attribute__((ext_vector_type(16))) float f32x16;
typedef unsigned short u16;

__device__ inline u16 bf16_rne(float x) {
  unsigned int u = __float_as_uint(x);
  return (u16)((u + 0x7FFFu + ((u >> 16) & 1u)) >> 16);
}
__device__ inline float bf16_tof(u16 h) {
  return __uint_as_float(((unsigned int)h) << 16);
}
__device__ inline void gll16(const void* g, void* l) {
  __builtin_amdgcn_global_load_lds(
      (const __attribute__((address_space(1))) unsigned int*)g,
      (__attribute__((address_space(3))) unsigned int*)l, 16, 0, 0);
}

// ---- cc[j] = sum_k codebook[j][k]^2 (bit-identical to r1-r6) --------------
__global__ __launch_bounds__(256) void cc_kernel(const float* __restrict__ cb,
                                                 float* __restrict__ cc) {
  int wave = threadIdx.x >> 6;
  int lane = threadIdx.x & 63;
  int row = blockIdx.x * 4 + wave;
  const float4 v = *(const float4*)(cb + (size_t)row * Kdim + lane * 4);
  float s = v.x * v.x + v.y * v.y + v.z * v.z + v.w * v.w;
  for (int off = 32; off; off >>= 1) s += __shfl_down(s, off);
  if (lane == 0) cc[row] = s;
}

// ---- codebook -> frag-order bf16 splits Cf (unchanged r4-r6) --------------
// Group (j32, arr, k16) of 512 u16 at ((j32*3+arr)*16 + k16)*512;
// within group: (khalf*32 + j%32)*8 + i.
__global__ __launch_bounds__(256) void conv_cb(const float* __restrict__ cb,
                                               u16* __restrict__ Cf) {
  const int g = blockIdx.x * 256 + threadIdx.x;   // 0 .. 8192*16-1
  const int j = g >> 4, k16 = g & 15;
  const float* src = cb + (size_t)j * Kdim + k16 * 16;
  float f[16];
#pragma unroll
  for (int q = 0; q < 4; ++q) {
    const float4 v = ((const float4*)src)[q];
    f[q * 4 + 0] = v.x; f[q * 4 + 1] = v.y; f[q * 4 + 2] = v.z; f[q * 4 + 3] = v.w;
  }
  u16 h[3][16];
#pragma unroll
  for (int i = 0; i < 16; ++i) {
    const u16 q0 = bf16_rne(f[i]);
    const float r1 = f[i] - bf16_tof(q0);
    const u16 q1 = bf16_rne(r1);
    const float r2 = r1 - bf16_tof(q1);
    h[0][i] = q0; h[1][i] = q1; h[2][i] = bf16_rne(r2);
  }
  const int j32 = j >> 5, li = j & 31;
#pragma unroll
  for (int arr = 0; arr < 3; ++arr) {
#pragma unroll
    for (int kh = 0; kh < 2; ++kh) {
      const size_t off = ((size_t)(j32 * 3 + arr) * 16 + k16) * 512 + (kh * 32 + li) * 8;
      *(int4*)(Cf + off) = *(int4*)&h[arr][kh * 8];
    }
  }
}

// ---- z (B,C,H,W) -> frag-order bf16 splits Zf + zz (unchanged r4-r6) ------
__global__ __launch_bounds__(256) void conv_z(const float* __restrict__ z,
                                              u16* __restrict__ Zf,
                                              float* __restrict__ zz) {
  __shared__ float tile[64][68];
  const int t = threadIdx.x;
  const int bid = blockIdx.x;
  const int n0 = bid * 64;
  const int b = bid >> 4;
  const int hw0 = (bid & 15) << 6;
  const float* zb = z + (size_t)b * (Kdim * HWsz) + hw0;
  float zzacc = 0.f;
  const int rr = t >> 2;
  const int kq = (t & 3) * 16;
  for (int kc = 0; kc < 4; ++kc) {
#pragma unroll
    for (int i = 0; i < 16; ++i) {
      const int idx = i * 256 + t;
      const int k = idx >> 6, r = idx & 63;
      tile[r][k] = zb[(size_t)(kc * 64 + k) * HWsz + r];
    }
    __syncthreads();
    if (t < 64) {
      for (int k = 0; k < 64; ++k) {
        const float a = tile[t][k];
        zzacc = fmaf(a, a, zzacc);
      }
    }
    u16 h[3][16];
#pragma unroll
    for (int i = 0; i < 16; ++i) {
      const float fv = tile[rr][kq + i];
      const u16 q0 = bf16_rne(fv);
      const float r1 = fv - bf16_tof(q0);
      const u16 q1 = bf16_rne(r1);
      const float r2 = r1 - bf16_tof(q1);
      h[0][i] = q0; h[1][i] = q1; h[2][i] = bf16_rne(r2);
    }
    const int k16 = kc * 4 + (t & 3);
    const int n32 = bid * 2 + (rr >> 5), li = rr & 31;
#pragma unroll
    for (int arr = 0; arr < 3; ++arr) {
#pragma unroll
      for (int kh = 0; kh < 2; ++kh) {
        const size_t off = ((size_t)(n32 * 3 + arr) * 16 + k16) * 512 + (kh * 32 + li) * 8;
        *(int4*)(Zf + off) = *(int4*)&h[arr][kh * 8];
      }
    }
    __syncthreads();
  }
  if (t < 64) zz[n0 + t] = zzacc;
}

// ---- main GEMM+argmin: z-rows persistent in VGPRs, codebook via LDS dbuf --
// Grid 512 = 128 rt x 4 cg, bid = rt*4+cg -> XCD=bid%8 serves only cg=x%4:
// the 3.15 MB Cf slice is the ONLY stream through that XCD's L2 -> resident.
// Block 256 thr / 4 waves, 2 blocks/CU (32 KB LDS). Wave holds B = its 32
// z-rows x 256 K x 3 limbs in 192 VGPRs; A-chunks (64 codes x 32 k x 3) are
// 6 KB gll16-staged, double-buffered, one barrier per chunk.
__global__ __launch_bounds__(256, 2) void vq_gemm(
    const u16* __restrict__ Cf, const u16* __restrict__ Zf,
    const float* __restrict__ cc, const float* __restrict__ zz,
    float* __restrict__ pd, int* __restrict__ pj) {
  __shared__ __align__(16) u16 Al[2][12288];   // 2 x 24 KB (4-kc chunks)
  __shared__ float ccs[2048];

  const int t = threadIdx.x;
  const int lane = t & 63;
  const int w = __builtin_amdgcn_readfirstlane(t >> 6);   // 0..3
  const int bid = blockIdx.x;
  const int cg = bid & 3;          // code slice (2048 codes), XCD-pinned
  const int rt = bid >> 2;         // row tile (128 rows)
  const int n32 = rt * 4 + w;      // this wave's 32-row group

#pragma unroll
  for (int i = 0; i < 8; ++i) ccs[i * 256 + t] = cc[cg * 2048 + i * 256 + t];

  const float zzv = zz[n32 * 32 + (lane & 31)];

  // B (z-rows) persistent: 16 kc x 3 limbs x bf16x8 = 192 VGPRs
  bf16x8 B[16][3];
#pragma unroll
  for (int kc = 0; kc < 16; ++kc)
#pragma unroll
    for (int arr = 0; arr < 3; ++arr)
      B[kc][arr] = *(const bf16x8*)(
          Zf + ((size_t)(n32 * 3 + arr) * 16 + kc) * 512 + lane * 8);

// stage chunk (gg, c_) of 64-code group gg into LDS slot sl: 24 groups of
// 1 KB, 6 per wave; dest = wave-uniform base + lane*16 (gll16 rule).
#define STAGE(gg, c_, sl)                                                     \
  if ((gg) < 32) {                                                            \
    _Pragma("unroll")                                                         \
    for (int i = 0; i < 6; ++i) {                                             \
      const int s = w * 6 + i;                                                \
      const int jx = s / 12, rem = s % 12;                                    \
      const int kc2 = rem / 3, arr = rem % 3;                                 \
      gll16(Cf + ((size_t)((cg * 64 + (gg) * 2 + jx) * 3 + arr) * 16 +        \
                  ((c_) * 4 + kc2)) * 512 + lane * 8,                         \
            &Al[sl][((jx * 4 + kc2) * 3 + arr) * 512]);                       \
    }                                                                         \
  }

// per kc: 6 A-frag b128 reads feed 12 MFMAs; per-acc-element product order
// (a0b0,a0b1,a1b0,a1b1,a0b2,a2b0) ascending kc — bit-identical to r3-r6.
#define MF(af, bv, ac) ac = __builtin_amdgcn_mfma_f32_32x32x16_bf16(af, bv, ac, 0, 0, 0);
#define CHUNK(sl, c_)                                                         \
  _Pragma("unroll")                                                           \
  for (int kc2 = 0; kc2 < 4; ++kc2) {                                         \
    bf16x8 a0[3], a1[3];                                                      \
    _Pragma("unroll")                                                         \
    for (int arr = 0; arr < 3; ++arr) {                                       \
      a0[arr] = *(const bf16x8*)&Al[sl][(kc2 * 3 + arr) * 512 + lane * 8];    \
      a1[arr] = *(const bf16x8*)&Al[sl][((4 + kc2) * 3 + arr) * 512 + lane * 8]; \
    }                                                                         \
    MF(a0[0], B[(c_) * 4 + kc2][0], acc0) MF(a1[0], B[(c_) * 4 + kc2][0], acc1) \
    MF(a0[0], B[(c_) * 4 + kc2][1], acc0) MF(a1[0], B[(c_) * 4 + kc2][1], acc1) \
    MF(a0[1], B[(c_) * 4 + kc2][0], acc0) MF(a1[1], B[(c_) * 4 + kc2][0], acc1) \
    MF(a0[1], B[(c_) * 4 + kc2][1], acc0) MF(a1[1], B[(c_) * 4 + kc2][1], acc1) \
    MF(a0[0], B[(c_) * 4 + kc2][2], acc0) MF(a1[0], B[(c_) * 4 + kc2][2], acc1) \
    MF(a0[2], B[(c_) * 4 + kc2][0], acc0) MF(a1[2], B[(c_) * 4 + kc2][0], acc1) \
  }

  STAGE(0, 0, 0)
  __syncthreads();

  float bd = INFINITY;
  int bj = 0;
  const f32x16 zero16 = {0,0,0,0,0,0,0,0,0,0,0,0,0,0,0,0};

  for (int g = 0; g < 32; ++g) {
    f32x16 acc0 = zero16, acc1 = zero16;
    // 4 chunks, statically double-buffered (4 chunks/group keeps parity)
    STAGE(g, 1, 1)      CHUNK(0, 0) __syncthreads();
    STAGE(g, 2, 0)      CHUNK(1, 1) __syncthreads();
    STAGE(g, 3, 1)      CHUNK(0, 2) __syncthreads();
    STAGE(g + 1, 0, 0)  CHUNK(1, 3) __syncthreads();

    // epilogue: d = (zz + cc) - 2*acc, ascending j (same expression r1-r6)
#pragma unroll
    for (int jx = 0; jx < 2; ++jx) {
      const f32x16& a = jx ? acc1 : acc0;
#pragma unroll
      for (int q = 0; q < 4; ++q) {
        const float4 c4 = *(const float4*)&ccs[g * 64 + jx * 32 + q * 8 + (lane >> 5) * 4];
        const float cv[4] = {c4.x, c4.y, c4.z, c4.w};
#pragma unroll
        for (int r = 0; r < 4; ++r) {
          const float d = (zzv + cv[r]) - 2.0f * a[q * 4 + r];
          const int j = cg * 2048 + g * 64 + jx * 32 + r + q * 8 + (lane >> 5) * 4;
          if (d < bd) { bd = d; bj = j; }
        }
      }
    }
  }
#undef STAGE
#undef CHUNK
#undef MF

  // combine lane halves (same z-row, complementary code sub-columns)
  {
    const float od = __shfl_xor(bd, 32);
    const int oj = __shfl_xor(bj, 32);
    if (od < bd || (od == bd && oj < bj)) { bd = od; bj = oj; }
  }
  if (lane < 32) {
    const int n = n32 * 32 + lane;
    pd[(size_t)cg * Nrows + n] = bd;
    pj[(size_t)cg * Nrows + n] = bj;
  }
}

// ---- combine NSPL code-group partials -> idx, counts ----------------------
__global__ __launch_bounds__(256) void vq_combine(const float* __restrict__ pd,
                                                  const int* __restrict__ pj,
                                                  int* __restrict__ idx_int,
                                                  float* __restrict__ out_idxf,
                                                  int* __restrict__ counts) {
  const int n = blockIdx.x * 256 + threadIdx.x;
  float d0 = pd[n];
  int j0 = pj[n];
  for (int s = 1; s < NSPL; ++s) {
    const float d = pd[(size_t)s * Nrows + n];
    const int j = pj[(size_t)s * Nrows + n];
    if (d < d0 || (d == d0 && j < j0)) { d0 = d; j0 = j; }
  }
  idx_int[n] = j0;
  out_idxf[n] = (float)j0;
  atomicAdd(&counts[j0], 1);
}

// ---- gather zq (BCHW) + loss sum (unchanged, passed r1-r6) ----------------
__global__ __launch_bounds__(256) void vq_gather_loss(
    const float* __restrict__ z, const float* __restrict__ cb,
    const int* __restrict__ idx_int, float* __restrict__ outz,
    float* __restrict__ loss_sum) {
  const int g = blockIdx.x * 256 + threadIdx.x;
  const int hw4 = g & 255;
  const int c = (g >> 8) & 255;
  const int b = g >> 16;
  const int n = b * HWsz + hw4 * 4;
  const float4 zv = *(const float4*)(z + (size_t)g * 4);
  const int4 j4 = *(const int4*)(idx_int + n);
  float4 q;
  q.x = cb[(size_t)j4.x * Kdim + c];
  q.y = cb[(size_t)j4.y * Kdim + c];
  q.z = cb[(size_t)j4.z * Kdim + c];
  q.w = cb[(size_t)j4.w * Kdim + c];
  *(float4*)(outz + (size_t)g * 4) = q;
  float dx = q.x - zv.x, dy = q.y - zv.y, dz = q.z - zv.z, dw = q.w - zv.w;
  float s = dx * dx + dy * dy + dz * dz + dw * dw;
  for (int off = 32; off; off >>= 1) s += __shfl_down(s, off);
  __shared__ float ws4[4];
  if ((threadIdx.x & 63) == 0) ws4[threadIdx.x >> 6] = s;
  __syncthreads();
  if (threadIdx.x == 0) atomicAdd(loss_sum, (ws4[0] + ws4[1]) + (ws4[2] + ws4[3]));
}

// ---- scalars (unchanged) --------------------------------------------------
__global__ __launch_bounds__(256) void vq_final(const int* __restrict__ counts,
                                                const float* __restrict__ loss_sum,
                                                float* __restrict__ out_sc) {
  float h = 0.f;
  for (int i = threadIdx.x; i < NE; i += 256) {
    float p = (float)counts[i] * (1.0f / 16384.0f);
    h += p * logf(p + 1e-10f);
  }
  for (int off = 32; off; off >>= 1) h += __shfl_down(h, off);
  __shared__ float hs[4];
  if ((threadIdx.x & 63) == 0) hs[threadIdx.x >> 6] = h;
  __syncthreads();
  if (threadIdx.x == 0) {
    float H = (hs[0] + hs[1]) + (hs[2] + hs[3]);
    float m = loss_sum[0] * (1.0f / 4194304.0f);
    out_sc[0] = m + BETAF * m;
    out_sc[1] = expf(-H);
  }
}

extern "C" void kernel_launch(void* const* d_in, const int* in_sizes, int n_in,
                              void* d_out, int out_size, void* d_ws, size_t ws_size,
                              hipStream_t stream) {
  const float* z = (const float*)d_in[0];
  const float* cb = (const float*)d_in[1];
  float* out = (float*)d_out;
  float* out_zq = out;                     // 4194304
  float* out_sc = out + 4194304;           // loss, perplexity
  float* out_idx = out + 4194306;          // 16384 idx as float

  char* wp = (char*)d_ws;
  u16* Cf = (u16*)wp;           wp += (size_t)NE * Kdim * 2 * 3;
  u16* Zf = (u16*)wp;           wp += (size_t)Nrows * Kdim * 2 * 3;
  float* cc = (float*)wp;       wp += (size_t)NE * 4;
  float* zz = (float*)wp;       wp += (size_t)Nrows * 4;
  float* pd = (float*)wp;       wp += (size_t)NSPL * Nrows * 4;
  int* pj = (int*)wp;           wp += (size_t)NSPL * Nrows * 4;
  int* idx_int = (int*)wp;      wp += (size_t)Nrows * 4;
  int* counts = (int*)wp;       wp += (size_t)NE * 4;
  float* loss_sum = (float*)wp; wp += 64;

  hipMemsetAsync(counts, 0, (size_t)NE * 4, stream);
  hipMemsetAsync(loss_sum, 0, 4, stream);

  cc_kernel<<<NE / 4, 256, 0, stream>>>(cb, cc);
  conv_cb<<<NE * 16 / 256, 256, 0, stream>>>(cb, Cf);
  conv_z<<<Nrows / 64, 256, 0, stream>>>(z, Zf, zz);
  vq_gemm<<<512, 256, 0, stream>>>(Cf, Zf, cc, zz, pd, pj);
  vq_combine<<<Nrows / 256, 256, 0, stream>>>(pd, pj, idx_int, out_idx, counts);
  vq_gather_loss<<<4096, 256, 0, stream>>>(z, cb, idx_int, out_zq, loss_sum);
  vq_final<<<1, 256, 0, stream>>>(counts, loss_sum, out_sc);
}